// Round 4
// baseline (248.240 us; speedup 1.0000x reference)
//
#include <hip/hip_runtime.h>

// VectorQuantizer: x [32,64,64,64] f32, emb [512,64] f32 -> out [32,64,64,64] f32
// out[b,:,h,w] = emb[argmin_k dists], reproducing numpy FLOAT32 bit semantics:
//   dists[k] = fl( fl(x_sq + e_sq[k]) - fl(2*dot[k]) ), dot = sequential-c FMA,
//   x_sq/e_sq = numpy pairwise-8 sums. absmax==0 verified (R2, R3).
//
// R4: same arithmetic, force x-vector residency in VGPRs.
//   R3 failure: VGPR_Count=40 — __launch_bounds__(256,4) only sets MIN
//   waves/EU; backend squeezed regs and sank the 64 x-loads into the k-loop
//   (~2.4x VALU inflation, VALUBusy 68%).
//   Fix: amdgpu_waves_per_eu(4,4) pins the target occupancy (=> 128-VGPR
//   budget), and an empty asm barrier on each xr[c] makes the loaded value's
//   producer opaque so it cannot be rematerialized from memory.

#define KNUM 512
#define CDIM 64
#define PPB  128   // pixels per block

__global__ __launch_bounds__(256)
__attribute__((amdgpu_waves_per_eu(4, 4)))
void vq_kernel(const float* __restrict__ x,
               const float* __restrict__ emb,
               float* __restrict__ out)
{
    const int tid  = threadIdx.x;
    const int lpix = tid & (PPB - 1);                 // pixel-in-block
    const int kh   = __builtin_amdgcn_readfirstlane(tid >> 7);  // k-half (uniform)
    const int pix  = blockIdx.x * PPB + lpix;         // 0..131071
    const int b    = pix >> 12;
    const int hw   = pix & 4095;
    const float* xp = x + (((size_t)b * CDIM) << 12) + hw;   // stride 4096 per c

    __shared__ __align__(16) float e_sq[KNUM];
    __shared__ float rbest[2][PPB];
    __shared__ int   ridx [2][PPB];

    // e_sq[k], numpy pairwise-8 semantics, cooperatively (2 rows/thread)
    for (int k = tid; k < KNUM; k += 256) {
        const float* e = emb + k * CDIM;
        float r[8];
        #pragma unroll
        for (int j = 0; j < 8; ++j) r[j] = __fmul_rn(e[j], e[j]);
        #pragma unroll
        for (int i = 8; i < CDIM; i += 8)
            #pragma unroll
            for (int j = 0; j < 8; ++j)
                r[j] = __fadd_rn(r[j], __fmul_rn(e[i + j], e[i + j]));
        e_sq[k] = __fadd_rn(
            __fadd_rn(__fadd_rn(r[0], r[1]), __fadd_rn(r[2], r[3])),
            __fadd_rn(__fadd_rn(r[4], r[5]), __fadd_rn(r[6], r[7])));
    }
    __syncthreads();

    // pixel vector -> VGPRs, then pin: opaque producer, cannot be re-loaded
    float xr[CDIM];
    #pragma unroll
    for (int c = 0; c < CDIM; ++c) xr[c] = xp[(size_t)c << 12];
    #pragma unroll
    for (int c = 0; c < CDIM; ++c) asm volatile("" : "+v"(xr[c]));

    // x_sq, numpy pairwise-8 semantics
    float xs;
    {
        float r[8];
        #pragma unroll
        for (int j = 0; j < 8; ++j) r[j] = __fmul_rn(xr[j], xr[j]);
        #pragma unroll
        for (int i = 8; i < CDIM; i += 8)
            #pragma unroll
            for (int j = 0; j < 8; ++j)
                r[j] = __fadd_rn(r[j], __fmul_rn(xr[i + j], xr[i + j]));
        xs = __fadd_rn(
            __fadd_rn(__fadd_rn(r[0], r[1]), __fadd_rn(r[2], r[3])),
            __fadd_rn(__fadd_rn(r[4], r[5]), __fadd_rn(r[6], r[7])));
    }

    // this wave-pair scans codes [kh*256, kh*256+256)
    const int k0 = kh << 8;
    float best = 3.4e38f;
    int bidx = k0;
    #pragma unroll 1
    for (int k = k0; k < k0 + 256; k += 4) {
        const float* e = emb + k * CDIM;              // uniform addr -> s_load
        const float4 es4 = *(const float4*)&e_sq[k];  // ds_read_b128
        float d0 = 0.f, d1 = 0.f, d2 = 0.f, d3 = 0.f;
        #pragma unroll
        for (int c = 0; c < CDIM; ++c) {
            const float xc = xr[c];
            d0 = fmaf(xc, e[c         ], d0);         // sequential-c = BLAS order
            d1 = fmaf(xc, e[c +   CDIM], d1);
            d2 = fmaf(xc, e[c + 2*CDIM], d2);
            d3 = fmaf(xc, e[c + 3*CDIM], d3);
        }
        const float s0 = __fsub_rn(__fadd_rn(xs, es4.x), __fmul_rn(2.0f, d0));
        const float s1 = __fsub_rn(__fadd_rn(xs, es4.y), __fmul_rn(2.0f, d1));
        const float s2 = __fsub_rn(__fadd_rn(xs, es4.z), __fmul_rn(2.0f, d2));
        const float s3 = __fsub_rn(__fadd_rn(xs, es4.w), __fmul_rn(2.0f, d3));
        if (s0 < best) { best = s0; bidx = k + 0; }   // strict < = first-min
        if (s1 < best) { best = s1; bidx = k + 1; }
        if (s2 < best) { best = s2; bidx = k + 2; }
        if (s3 < best) { best = s3; bidx = k + 3; }
    }

    rbest[kh][lpix] = best;
    ridx [kh][lpix] = bidx;
    __syncthreads();

    // combine halves: half1 wins only if strictly smaller (lower k on ties)
    const float b0 = rbest[0][lpix], b1 = rbest[1][lpix];
    const int widx = (b1 < b0) ? ridx[1][lpix] : ridx[0][lpix];

    // gather: each half-thread writes 32 channels (bit-exact emb row copy)
    const float* eb = emb + widx * CDIM + (kh << 5);
    float* op = out + (((size_t)b * CDIM) << 12) + ((size_t)(kh << 5) << 12) + hw;
    #pragma unroll
    for (int c = 0; c < 32; ++c) op[(size_t)c << 12] = eb[c];
}

extern "C" void kernel_launch(void* const* d_in, const int* in_sizes, int n_in,
                              void* d_out, int out_size, void* d_ws, size_t ws_size,
                              hipStream_t stream)
{
    const float* x   = (const float*)d_in[0];
    const float* emb = (const float*)d_in[1];
    float* out = (float*)d_out;
    const int nblocks = (32 * 64 * 64) / PPB;   // 1024
    hipLaunchKernelGGL(vq_kernel, dim3(nblocks), dim3(256), 0, stream, x, emb, out);
}